// Round 5
// baseline (157.061 us; speedup 1.0000x reference)
//
#include <hip/hip_runtime.h>
#include <hip/hip_bf16.h>

#define SEQ 4096
#define DIM 512
#define SCALE 0.044194173824159216f  // 1/sqrt(512)

#define SPLITS 4
#define BQ 64
#define KVBLK 64
#define KEYS_PER_SPLIT (SEQ / SPLITS)    // 1024
#define ITERS (KEYS_PER_SPLIT / KVBLK)   // 16
#define THR_DEFER 8.0f

typedef __attribute__((ext_vector_type(8))) short short8;
typedef __attribute__((ext_vector_type(4))) float f32x4;
typedef __attribute__((ext_vector_type(4))) unsigned int u32x4;

__device__ __forceinline__ short f2bf(float f) {
  union { float f; unsigned u; } c; c.f = f;
  unsigned u = c.u;
  return (short)((u + 0x7FFFu + ((u >> 16) & 1u)) >> 16);
}

__device__ __forceinline__ short8 pack8(float4 a, float4 b) {
  short8 r;
  r[0] = f2bf(a.x); r[1] = f2bf(a.y); r[2] = f2bf(a.z); r[3] = f2bf(a.w);
  r[4] = f2bf(b.x); r[5] = f2bf(b.y); r[6] = f2bf(b.z); r[7] = f2bf(b.w);
  return r;
}

__device__ __forceinline__ unsigned pkbf(float lo, float hi) {
  return ((unsigned)(unsigned short)f2bf(hi) << 16) | (unsigned short)f2bf(lo);
}

// async global->LDS, 16B per lane, dest = uniform base + lane*16
__device__ __forceinline__ void gload16(const void* g, void* l) {
  __builtin_amdgcn_global_load_lds(
      (const __attribute__((address_space(1))) unsigned int*)g,
      (__attribute__((address_space(3))) unsigned int*)l, 16, 0, 0);
}

// ---------- prep: fp32 -> bf16 row-major (for K) ----------
__global__ void cvt_bf16(const float* __restrict__ in, ushort* __restrict__ ob, int n8) {
  int i = blockIdx.x * blockDim.x + threadIdx.x;
  if (i >= n8) return;
  const float4* p = (const float4*)(in + (size_t)i * 8);
  short8 v = pack8(p[0], p[1]);
  *(short8*)(ob + (size_t)i * 8) = v;
}

// ---------- prep: fp32 V (S x D) -> bf16 V^T (D x S) ----------
__global__ void transpose_bf16(const float* __restrict__ v, ushort* __restrict__ vt) {
  __shared__ float t[64][65];
  const int bs = blockIdx.x % (SEQ / 64);
  const int bd = blockIdx.x / (SEQ / 64);
  const int s0 = bs * 64, d0 = bd * 64;
  const int tid = threadIdx.x;
#pragma unroll
  for (int k = 0; k < 16; ++k) {
    int idx = k * 256 + tid;
    int r = idx >> 6, c = idx & 63;
    t[r][c] = v[(size_t)(s0 + r) * DIM + d0 + c];
  }
  __syncthreads();
#pragma unroll
  for (int k = 0; k < 16; ++k) {
    int idx = k * 256 + tid;
    int dr = idx >> 6, sc = idx & 63;
    vt[(size_t)(d0 + dr) * SEQ + s0 + sc] = (ushort)f2bf(t[sc][dr]);
  }
}

// ---------- fused attention: independent-wave flash workers ----------
// 8 waves: rg = w&3 (q-rows rg*16..+16), kh = w>>2 (keys kh*32 of each 64-key tile).
// Each wave: Q + O + (m,l) fully in registers; swapped QK^T (mfma(K,Q) -> S^T)
// makes softmax in-wave. Waves share only the staged kt/vtt LDS tiles.
__global__ __launch_bounds__(512, 2) void attn_split(
    const float* __restrict__ q, const ushort* __restrict__ kbf,
    const ushort* __restrict__ vt, float* __restrict__ opart,
    float* __restrict__ ml) {
  __shared__ __align__(16) ushort kt[KVBLK * DIM];   // 64 KB, chunk16 ^= row&31
  __shared__ __align__(16) ushort vtt[DIM * KVBLK];  // 64 KB, granule16 ^= row&7
  __shared__ float mst[2][2][BQ];                    // [kh][m|l][row], 1 KB

  const int tid  = threadIdx.x;
  const int lane = tid & 63;
  const int w    = tid >> 6;
  const int lr   = lane & 15;
  const int lg   = lane >> 4;
  const int sp   = blockIdx.x & (SPLITS - 1);
  const int qb   = blockIdx.x >> 2;
  const int rg   = w & 3;
  const int kh   = w >> 2;
  const int qrow0 = qb * BQ;
  const int kbase = sp * KEYS_PER_SPLIT;

  // Q fragments: B-operand (col=qrow=lr, k=lg*8+j) — same layout as A-frag load
  short8 qf[16];
  {
    const float* qp = q + (size_t)(qrow0 + rg * 16 + lr) * DIM + lg * 8;
#pragma unroll
    for (int c = 0; c < 16; ++c)
      qf[c] = pack8(*(const float4*)(qp + c * 32), *(const float4*)(qp + c * 32 + 4));
  }
  f32x4 oacc[32] = {};
  float m_reg = -INFINITY, l_reg = 0.f;

  // K rows 1KB: LDS[r][ch16] = K[kb+r][ch16 ^ (r&31)]; 8 gloads/wave
  auto stageK = [&](int kb) {
#pragma unroll
    for (int i = 0; i < 8; ++i) {
      int r = w * 8 + i;
      const ushort* src = kbf + (size_t)(kb + r) * DIM + ((lane ^ (r & 31)) * 8);
      gload16(src, &kt[r * DIM]);
    }
  };
  // V^T rows 128B (8 granules of 16B): LDS[r][g] = vt[r][kb + (g^(r&7))*8..]
  auto stageV = [&](int kb) {
#pragma unroll
    for (int j = 0; j < 8; ++j) {
      int r0 = w * 64 + j * 8;
      int rr = r0 + (lane >> 3);
      const ushort* src = vt + (size_t)rr * SEQ + kb + (((lane & 7) ^ (rr & 7)) * 8);
      gload16(src, &vtt[r0 * KVBLK]);
    }
  };

  stageK(kbase);  // K(0) in flight

#pragma unroll 1
  for (int it = 0; it < ITERS; ++it) {
    const int kb = kbase + it * KVBLK;

    stageV(kb);  // V(t) in flight; lands during QK/softmax
    asm volatile("s_waitcnt vmcnt(8)" ::: "memory");  // K(t) landed
    __builtin_amdgcn_s_barrier();                     // bar-a: kt(t) ready

    // ---- swapped QK^T: S^T[key][qrow], wave's 32 keys = 2 subtiles of 16 ----
    f32x4 s0 = {}, s1 = {};
    {
      const int kr0 = kh * 32 + lr;
      const int kr1 = kr0 + 16;
      const char* kb0 = (const char*)kt + kr0 * 1024;
      const char* kb1 = (const char*)kt + kr1 * 1024;
      const int sw0 = kr0 & 31, sw1 = kr1 & 31;
      __builtin_amdgcn_s_setprio(1);
#pragma unroll
      for (int c = 0; c < 16; ++c) {
        short8 k0 = *(const short8*)(kb0 + (((c * 4 + lg) ^ sw0) << 4));
        short8 k1 = *(const short8*)(kb1 + (((c * 4 + lg) ^ sw1) << 4));
        s0 = __builtin_amdgcn_mfma_f32_16x16x32_bf16(k0, qf[c], s0, 0, 0, 0);
        s1 = __builtin_amdgcn_mfma_f32_16x16x32_bf16(k1, qf[c], s1, 0, 0, 0);
      }
      __builtin_amdgcn_s_setprio(0);
    }
    __builtin_amdgcn_s_barrier();  // bar-b: all waves done reading kt(t)

    if (it + 1 < ITERS) stageK(kb + KVBLK);  // kt free; K(t+1) lands during PV

    // ---- in-wave online softmax (lane owns q-row lr; keys split over lg) ----
    short8 pf;
    {
      float sc0[4], sc1[4];
#pragma unroll
      for (int r = 0; r < 4; ++r) { sc0[r] = s0[r] * SCALE; sc1[r] = s1[r] * SCALE; }
      float tmax = fmaxf(fmaxf(fmaxf(sc0[0], sc0[1]), fmaxf(sc0[2], sc0[3])),
                         fmaxf(fmaxf(sc1[0], sc1[1]), fmaxf(sc1[2], sc1[3])));
      tmax = fmaxf(tmax, __shfl_xor(tmax, 16));
      tmax = fmaxf(tmax, __shfl_xor(tmax, 32));
      // T13 defer-max: rescale only when some row grew past THR
      if (__ballot(tmax - m_reg > THR_DEFER) != 0ull) {
        float mnew = fmaxf(m_reg, tmax);
        float osc = __expf(m_reg - mnew);   // -inf -> 0 on first tile
        m_reg = mnew;
        l_reg *= osc;
        float o0 = __shfl(osc, lg * 4 + 0);
        float o1 = __shfl(osc, lg * 4 + 1);
        float o2 = __shfl(osc, lg * 4 + 2);
        float o3 = __shfl(osc, lg * 4 + 3);
#pragma unroll
        for (int ct = 0; ct < 32; ++ct) {
          oacc[ct][0] *= o0; oacc[ct][1] *= o1;
          oacc[ct][2] *= o2; oacc[ct][3] *= o3;
        }
      }
      float p0[4], p1[4];
#pragma unroll
      for (int r = 0; r < 4; ++r) {
        p0[r] = __expf(sc0[r] - m_reg);
        p1[r] = __expf(sc1[r] - m_reg);
      }
      float ps = ((p0[0] + p0[1]) + (p0[2] + p0[3])) +
                 ((p1[0] + p1[1]) + (p1[2] + p1[3]));
      ps += __shfl_xor(ps, 16);
      ps += __shfl_xor(ps, 32);
      l_reg += ps;
      // pack P (bf16 pairs) and redistribute to PV A-frag layout
      // lane holds P[qrow=lr][keys lg*4+r (st0), 16+lg*4+r (st1)]
      unsigned d0 = pkbf(p0[0], p0[1]), d1 = pkbf(p0[2], p0[3]);
      unsigned d2 = pkbf(p1[0], p1[1]), d3 = pkbf(p1[2], p1[3]);
      int srcA = lr + ((lg & 1) << 5);
      int srcB = srcA + 16;
      unsigned xA0 = __shfl((int)d0, srcA), xA2 = __shfl((int)d2, srcA);
      unsigned xA1 = __shfl((int)d1, srcA), xA3 = __shfl((int)d3, srcA);
      unsigned xB0 = __shfl((int)d0, srcB), xB2 = __shfl((int)d2, srcB);
      unsigned xB1 = __shfl((int)d1, srcB), xB3 = __shfl((int)d3, srcB);
      bool hi = (lg >> 1) != 0;
      union { short8 s8; u32x4 u4; } pu;
      pu.u4[0] = hi ? xA2 : xA0;
      pu.u4[1] = hi ? xA3 : xA1;
      pu.u4[2] = hi ? xB2 : xB0;
      pu.u4[3] = hi ? xB3 : xB1;
      pf = pu.s8;
    }

    if (it + 1 < ITERS) {
      asm volatile("s_waitcnt vmcnt(8)" ::: "memory");  // V(t) landed
    } else {
      asm volatile("s_waitcnt vmcnt(0)" ::: "memory");
    }
    __builtin_amdgcn_s_barrier();  // bar-c: vtt(t) ready

    // ---- PV: O[qrow][d] += P[qrow][keys kh*32..+32] * V ----
    {
      __builtin_amdgcn_s_setprio(1);
#pragma unroll
      for (int ct = 0; ct < 32; ++ct) {
        int vr = ct * 16 + lr;
        short8 vf = *(const short8*)((const char*)vtt + vr * 128 +
                                     (((kh * 4 + lg) ^ (lr & 7)) << 4));
        oacc[ct] = __builtin_amdgcn_mfma_f32_16x16x32_bf16(pf, vf, oacc[ct], 0, 0, 0);
      }
      __builtin_amdgcn_s_setprio(0);
    }
    __builtin_amdgcn_s_barrier();  // bar-d: all waves done reading vtt(t)
  }

  // ---- epilogue: merge kh halves via LDS (reuse kt/vtt), write opart + ml ----
  if (lane < 16) {
    mst[kh][0][rg * 16 + lane] = m_reg;
    mst[kh][1][rg * 16 + lane] = l_reg;
  }
  __syncthreads();
  {
    float wgt[4];
#pragma unroll
    for (int r = 0; r < 4; ++r) {
      int row = rg * 16 + lg * 4 + r;
      float m0 = mst[0][0][row], m1 = mst[1][0][row];
      float Mx = fmaxf(m0, m1);
      wgt[r] = __expf((kh ? m1 : m0) - Mx);
    }
#pragma unroll
    for (int ct = 0; ct < 32; ++ct)
#pragma unroll
      for (int r = 0; r < 4; ++r) oacc[ct][r] *= wgt[r];

    float* stg = (rg < 2) ? (float*)kt + rg * 8192 : (float*)vtt + (rg - 2) * 8192;
    if (kh == 1) {
#pragma unroll
      for (int ct = 0; ct < 32; ++ct)
#pragma unroll
        for (int r = 0; r < 4; ++r)
          stg[(lg * 4 + r) * DIM + ct * 16 + lr] = oacc[ct][r];
    }
  }
  __syncthreads();
  if (kh == 0) {
    const float* stg = (rg < 2) ? (float*)kt + rg * 8192 : (float*)vtt + (rg - 2) * 8192;
    float* op = opart + ((size_t)sp * SEQ + qrow0 + rg * 16) * DIM;
#pragma unroll
    for (int ct = 0; ct < 32; ++ct)
#pragma unroll
      for (int r = 0; r < 4; ++r)
        op[(size_t)(lg * 4 + r) * DIM + ct * 16 + lr] =
            oacc[ct][r] + stg[(lg * 4 + r) * DIM + ct * 16 + lr];
    if (lane < 16) {
      int row = rg * 16 + lane;
      float m0 = mst[0][0][row], m1 = mst[1][0][row];
      float Mx = fmaxf(m0, m1);
      float ls = mst[0][1][row] * __expf(m0 - Mx) + mst[1][1][row] * __expf(m1 - Mx);
      size_t base = ((size_t)sp * SEQ + qrow0 + row) * 2;
      ml[base] = Mx;
      ml[base + 1] = ls;
    }
  }
}

// ---------- combine split partials ----------
__global__ void combine(const float* __restrict__ opart, const float* __restrict__ ml,
                        float* __restrict__ out) {
  int gid = blockIdx.x * 256 + threadIdx.x;
  int row = gid >> 7;
  int dv  = (gid & 127) * 4;
  float m[SPLITS], l[SPLITS], wgt[SPLITS];
  float M = -INFINITY;
#pragma unroll
  for (int i = 0; i < SPLITS; ++i) {
    m[i] = ml[((size_t)i * SEQ + row) * 2];
    l[i] = ml[((size_t)i * SEQ + row) * 2 + 1];
    M = fmaxf(M, m[i]);
  }
  float L = 0.f;
#pragma unroll
  for (int i = 0; i < SPLITS; ++i) { wgt[i] = __expf(m[i] - M); L += l[i] * wgt[i]; }
  float inv = 1.f / L;
  float4 acc = {0.f, 0.f, 0.f, 0.f};
#pragma unroll
  for (int i = 0; i < SPLITS; ++i) {
    float4 o = *(const float4*)(opart + ((size_t)i * SEQ + row) * DIM + dv);
    acc.x += o.x * wgt[i]; acc.y += o.y * wgt[i];
    acc.z += o.z * wgt[i]; acc.w += o.w * wgt[i];
  }
  acc.x *= inv; acc.y *= inv; acc.z *= inv; acc.w *= inv;
  *(float4*)(out + (size_t)row * DIM + dv) = acc;
}

// ---------- fallback if ws too small ----------
__global__ __launch_bounds__(512) void attn_fused_fb(
    const float* __restrict__ q, const float* __restrict__ k,
    const float* __restrict__ v, float* __restrict__ out) {
  __shared__ float s_lds[16][128];
  __shared__ __align__(16) unsigned short p_lds[16 * 128];
  __shared__ float m_st[16], l_st[16], osc_st[16];
  const int tid = threadIdx.x, lane = tid & 63, w = tid >> 6;
  const int lr = lane & 15, lg = lane >> 4, qb = blockIdx.x * 16;
  if (tid < 16) { m_st[tid] = -INFINITY; l_st[tid] = 0.f; }
  short8 qf[16];
  {
    const float* qp = q + (size_t)(qb + lr) * DIM + lg * 8;
#pragma unroll
    for (int c = 0; c < 16; ++c)
      qf[c] = pack8(*(const float4*)(qp + c * 32), *(const float4*)(qp + c * 32 + 4));
  }
  f32x4 oacc[4] = {};
  __syncthreads();
  for (int it = 0; it < SEQ / 128; ++it) {
    const int kb = it * 128;
    {
      const float* kp = k + (size_t)(kb + w * 16 + lr) * DIM + lg * 8;
      f32x4 sacc = {};
#pragma unroll
      for (int c = 0; c < 16; ++c) {
        short8 kf = pack8(*(const float4*)(kp + c * 32), *(const float4*)(kp + c * 32 + 4));
        sacc = __builtin_amdgcn_mfma_f32_16x16x32_bf16(qf[c], kf, sacc, 0, 0, 0);
      }
#pragma unroll
      for (int r = 0; r < 4; ++r) s_lds[lg * 4 + r][w * 16 + lr] = sacc[r] * SCALE;
    }
    __syncthreads();
    {
      const int srow = tid >> 5, sj = tid & 31;
      float4 sv = *(const float4*)&s_lds[srow][sj * 4];
      float tmax = fmaxf(fmaxf(sv.x, sv.y), fmaxf(sv.z, sv.w));
#pragma unroll
      for (int m = 16; m >= 1; m >>= 1) tmax = fmaxf(tmax, __shfl_xor(tmax, m));
      float mold = m_st[srow], mnew = fmaxf(mold, tmax);
      float p0 = __expf(sv.x - mnew), p1 = __expf(sv.y - mnew);
      float p2 = __expf(sv.z - mnew), p3 = __expf(sv.w - mnew);
      float psum = (p0 + p1) + (p2 + p3);
#pragma unroll
      for (int m = 16; m >= 1; m >>= 1) psum += __shfl_xor(psum, m);
      if (sj == 0) {
        float sc = __expf(mold - mnew);
        l_st[srow] = l_st[srow] * sc + psum; m_st[srow] = mnew; osc_st[srow] = sc;
      }
      ushort4 pb;
      pb.x = (unsigned short)f2bf(p0); pb.y = (unsigned short)f2bf(p1);
      pb.z = (unsigned short)f2bf(p2); pb.w = (unsigned short)f2bf(p3);
      int lin = srow * 256 + sj * 8;
      *(ushort4*)((char*)p_lds + (lin ^ ((srow & 7) << 4))) = pb;
    }
    __syncthreads();
    {
      float osc[4];
#pragma unroll
      for (int r = 0; r < 4; ++r) osc[r] = osc_st[lg * 4 + r];
#pragma unroll
      for (int ct = 0; ct < 4; ++ct)
#pragma unroll
        for (int r = 0; r < 4; ++r) oacc[ct][r] *= osc[r];
#pragma unroll
      for (int kc = 0; kc < 4; ++kc) {
        int lin = lr * 256 + (kc * 32 + 8 * lg) * 2;
        short8 pf = *(const short8*)((const char*)p_lds + (lin ^ ((lr & 7) << 4)));
        const float* vp0 = v + (size_t)(kb + kc * 32 + 8 * lg) * DIM + w * 64 + lr;
#pragma unroll
        for (int ct = 0; ct < 4; ++ct) {
          const float* vp = vp0 + ct * 16;
          short8 vf;
#pragma unroll
          for (int jj = 0; jj < 8; ++jj) vf[jj] = f2bf(vp[(size_t)jj * DIM]);
          oacc[ct] = __builtin_amdgcn_mfma_f32_16x16x32_bf16(pf, vf, oacc[ct], 0, 0, 0);
        }
      }
    }
    __syncthreads();
  }
  {
    float linv[4];
#pragma unroll
    for (int r = 0; r < 4; ++r) linv[r] = 1.f / l_st[lg * 4 + r];
#pragma unroll
    for (int ct = 0; ct < 4; ++ct)
#pragma unroll
      for (int r = 0; r < 4; ++r)
        out[(size_t)(qb + lg * 4 + r) * DIM + w * 64 + ct * 16 + lr] =
            oacc[ct][r] * linv[r];
  }
}

extern "C" void kernel_launch(void* const* d_in, const int* in_sizes, int n_in,
                              void* d_out, int out_size, void* d_ws, size_t ws_size,
                              hipStream_t stream) {
  (void)in_sizes; (void)n_in; (void)out_size;
  const float* q = (const float*)d_in[0];
  const float* k = (const float*)d_in[1];
  const float* v = (const float*)d_in[2];
  float* out = (float*)d_out;

  const size_t kbf_elems = (size_t)SEQ * DIM;
  const size_t vt_elems  = (size_t)DIM * SEQ;
  const size_t op_elems  = (size_t)SPLITS * SEQ * DIM;
  const size_t ml_elems  = (size_t)SPLITS * SEQ * 2;
  const size_t need = kbf_elems * 2 + vt_elems * 2 + op_elems * 4 + ml_elems * 4;

  if (ws_size >= need) {
    ushort* kbf  = (ushort*)d_ws;
    ushort* vtb  = kbf + kbf_elems;
    float* opart = (float*)(vtb + vt_elems);
    float* ml    = opart + op_elems;

    cvt_bf16<<<(SEQ * DIM / 8 + 255) / 256, 256, 0, stream>>>(k, kbf, SEQ * DIM / 8);
    transpose_bf16<<<(SEQ / 64) * (DIM / 64), 256, 0, stream>>>(v, vtb);
    attn_split<<<(SEQ / BQ) * SPLITS, 512, 0, stream>>>(q, kbf, vtb, opart, ml);
    combine<<<(SEQ * DIM / 4) / 256, 256, 0, stream>>>(opart, ml, out);
  } else {
    attn_fused_fb<<<SEQ / 16, 512, 0, stream>>>(q, k, v, out);
  }
}

// Round 6
// 86.832 us; speedup vs baseline: 1.8088x; 1.8088x over previous
//
#include <hip/hip_runtime.h>
#include <hip/hip_bf16.h>

#define SEQ 4096
#define DIM 512
#define SCALE 0.044194173824159216f  // 1/sqrt(512)

#define SPLITS 4
#define BQ 64
#define KVBLK 64
#define KEYS_PER_SPLIT (SEQ / SPLITS)    // 1024
#define ITERS (KEYS_PER_SPLIT / KVBLK)   // 16
#define THR_DEFER 8.0f

typedef __attribute__((ext_vector_type(8))) short short8;
typedef __attribute__((ext_vector_type(4))) float f32x4;
typedef __attribute__((ext_vector_type(16))) float f32x16;

__device__ __forceinline__ short f2bf(float f) {
  union { float f; unsigned u; } c; c.f = f;
  unsigned u = c.u;
  return (short)((u + 0x7FFFu + ((u >> 16) & 1u)) >> 16);
}

__device__ __forceinline__ short8 pack8(float4 a, float4 b) {
  short8 r;
  r[0] = f2bf(a.x); r[1] = f2bf(a.y); r[2] = f2bf(a.z); r[3] = f2bf(a.w);
  r[4] = f2bf(b.x); r[5] = f2bf(b.y); r[6] = f2bf(b.z); r[7] = f2bf(b.w);
  return r;
}

__device__ __forceinline__ ushort4 pack4(float a, float b, float c, float d) {
  ushort4 r;
  r.x = (unsigned short)f2bf(a); r.y = (unsigned short)f2bf(b);
  r.z = (unsigned short)f2bf(c); r.w = (unsigned short)f2bf(d);
  return r;
}

// async global->LDS, 16B per lane, dest = uniform base + lane*16
__device__ __forceinline__ void gload16(const void* g, void* l) {
  __builtin_amdgcn_global_load_lds(
      (const __attribute__((address_space(1))) unsigned int*)g,
      (__attribute__((address_space(3))) unsigned int*)l, 16, 0, 0);
}

// ---------- prep: fp32 -> bf16 row-major (for K) ----------
__global__ void cvt_bf16(const float* __restrict__ in, ushort* __restrict__ ob, int n8) {
  int i = blockIdx.x * blockDim.x + threadIdx.x;
  if (i >= n8) return;
  const float4* p = (const float4*)(in + (size_t)i * 8);
  short8 v = pack8(p[0], p[1]);
  *(short8*)(ob + (size_t)i * 8) = v;
}

// ---------- prep: fp32 V (S x D) -> bf16 V^T (D x S) ----------
__global__ void transpose_bf16(const float* __restrict__ v, ushort* __restrict__ vt) {
  __shared__ float t[64][65];
  const int bs = blockIdx.x % (SEQ / 64);
  const int bd = blockIdx.x / (SEQ / 64);
  const int s0 = bs * 64, d0 = bd * 64;
  const int tid = threadIdx.x;
#pragma unroll
  for (int k = 0; k < 16; ++k) {
    int idx = k * 256 + tid;
    int r = idx >> 6, c = idx & 63;
    t[r][c] = v[(size_t)(s0 + r) * DIM + d0 + c];
  }
  __syncthreads();
#pragma unroll
  for (int k = 0; k < 16; ++k) {
    int idx = k * 256 + tid;
    int dr = idx >> 6, sc = idx & 63;
    vt[(size_t)(d0 + dr) * SEQ + s0 + sc] = (ushort)f2bf(t[sc][dr]);
  }
}

// ---------- fused attention ----------
// QK role:  rg = w&3 (16 q-rows), kh = w>>2 (32-key half). Swapped QK^T
//           (mfma(K,Q) -> S^T) => in-register softmax; cross-kh max merge
//           via tiny mx_st LDS exchange (folded into existing barrier).
// PV role:  rg_pv = w&1 (32 q-rows), cg = w>>1 (128 out cols), 32x32x16 MFMA,
//           P from p_lds (bf16), V from vtt. O = 4 x f32x16 = 64 VGPR.
__global__ __launch_bounds__(512, 2) void attn_split(
    const float* __restrict__ q, const ushort* __restrict__ kbf,
    const ushort* __restrict__ vt, float* __restrict__ opart,
    float* __restrict__ ml) {
  __shared__ __align__(16) ushort kt[KVBLK * DIM];    // 64 KB, granule16 ^= row&31
  __shared__ __align__(16) ushort vtt[DIM * KVBLK];   // 64 KB, granule16 ^= row&7
  __shared__ __align__(16) ushort p_lds[BQ * KVBLK];  // 8 KB,  byte ^= (row&7)<<4
  __shared__ float mx_st[2][BQ];                      // per-kh tile max exchange
  __shared__ float osc_st[BQ];                        // per-row rescale factor
  __shared__ float l_st[2][BQ];                       // epilogue l merge
  __shared__ int   flag_st[4];                        // per 16-row strip: rescaled?

  const int tid  = threadIdx.x;
  const int lane = tid & 63;
  const int w    = tid >> 6;
  const int lr   = lane & 15;
  const int lg   = lane >> 4;
  const int l31  = lane & 31;
  const int hi   = lane >> 5;
  const int sp   = blockIdx.x & (SPLITS - 1);
  const int qb   = blockIdx.x >> 2;
  const int rg   = w & 3;    // QK row-group (16 rows)
  const int kh   = w >> 2;   // QK key-half (32 keys)
  const int rg_pv = w & 1;   // PV row-group (32 rows)
  const int cg    = w >> 1;  // PV col-group (128 cols)
  const int qrow0 = qb * BQ;
  const int kbase = sp * KEYS_PER_SPLIT;

  // Q fragments (B-operand 16x16x32): col=qrow=lr, k=lg*8+j  [round-5 proven]
  short8 qf[16];
  {
    const float* qp = q + (size_t)(qrow0 + rg * 16 + lr) * DIM + lg * 8;
#pragma unroll
    for (int c = 0; c < 16; ++c)
      qf[c] = pack8(*(const float4*)(qp + c * 32), *(const float4*)(qp + c * 32 + 4));
  }
  f32x16 oacc[4] = {};
  float m_reg = -INFINITY, l_reg = 0.f;

  // K rows 1KB: LDS[r][g16] = K[kb+r][(g16 ^ (r&31))*8..]; 8 gloads/wave
  auto stageK = [&](int kb) {
#pragma unroll
    for (int i = 0; i < 8; ++i) {
      int r = w * 8 + i;
      const ushort* src = kbf + (size_t)(kb + r) * DIM + ((lane ^ (r & 31)) * 8);
      gload16(src, &kt[r * DIM]);
    }
  };
  // V^T rows 128B: LDS[d][g] = vt[d][kb + ((g^(d&7))*8)..]; 8 gloads/wave
  auto stageV = [&](int kb) {
#pragma unroll
    for (int j = 0; j < 8; ++j) {
      int r0 = w * 64 + j * 8;
      int rr = r0 + (lane >> 3);
      const ushort* src = vt + (size_t)rr * SEQ + kb + (((lane & 7) ^ (rr & 7)) * 8);
      gload16(src, &vtt[r0 * KVBLK]);
    }
  };

  stageK(kbase);  // K(0) in flight

#pragma unroll 1
  for (int it = 0; it < ITERS; ++it) {
    const int kb = kbase + it * KVBLK;

    stageV(kb);  // V(t) in flight; lands during QK/softmax
    asm volatile("s_waitcnt vmcnt(8)" ::: "memory");  // K(t) landed (V=8 out)
    __builtin_amdgcn_s_barrier();                     // bar-A: kt(t) ready

    // ---- swapped QK^T (16x16x32): S^T[key][qrow] for wave's 32 keys ----
    f32x4 s0 = {}, s1 = {};
    {
      const int kr0 = kh * 32 + lr;
      const int kr1 = kr0 + 16;
      const char* kb0 = (const char*)kt + kr0 * 1024;
      const char* kb1 = (const char*)kt + kr1 * 1024;
      const int sw0 = kr0 & 31, sw1 = kr1 & 31;
      __builtin_amdgcn_s_setprio(1);
#pragma unroll
      for (int c = 0; c < 16; ++c) {
        short8 k0 = *(const short8*)(kb0 + (((c * 4 + lg) ^ sw0) << 4));
        short8 k1 = *(const short8*)(kb1 + (((c * 4 + lg) ^ sw1) << 4));
        s0 = __builtin_amdgcn_mfma_f32_16x16x32_bf16(k0, qf[c], s0, 0, 0, 0);
        s1 = __builtin_amdgcn_mfma_f32_16x16x32_bf16(k1, qf[c], s1, 0, 0, 0);
      }
      __builtin_amdgcn_s_setprio(0);
    }

    // per-row tile max over wave's 32 keys (lane owns qrow=lr)
    float sc0[4], sc1[4];
#pragma unroll
    for (int r = 0; r < 4; ++r) { sc0[r] = s0[r] * SCALE; sc1[r] = s1[r] * SCALE; }
    float tmax = fmaxf(fmaxf(fmaxf(sc0[0], sc0[1]), fmaxf(sc0[2], sc0[3])),
                       fmaxf(fmaxf(sc1[0], sc1[1]), fmaxf(sc1[2], sc1[3])));
    tmax = fmaxf(tmax, __shfl_xor(tmax, 16));
    tmax = fmaxf(tmax, __shfl_xor(tmax, 32));
    if (lane < 16) mx_st[kh][rg * 16 + lane] = tmax;

    asm volatile("s_waitcnt lgkmcnt(0)" ::: "memory");
    __builtin_amdgcn_s_barrier();                     // bar-B: kt consumed, mx visible

    if (it + 1 < ITERS) stageK(kb + KVBLK);  // K(t+1) lands during PV

    // ---- softmax finish: common m across kh pair, defer-max, P -> LDS ----
    {
      const int row = rg * 16 + lr;
      float tmax64 = fmaxf(mx_st[0][row], mx_st[1][row]);
      bool resc = tmax64 > m_reg + THR_DEFER;
      float mnew = resc ? tmax64 : m_reg;
      float osc = __expf(m_reg - mnew);  // 1.0 when deferred; 0 on first tile
      unsigned long long bl = __ballot(resc);
      if (kh == 0 && lane == 0) flag_st[rg] = (bl != 0ull) ? 1 : 0;
      if (kh == 0 && lane < 16) osc_st[row] = osc;
      m_reg = mnew;
      l_reg *= osc;
      float p0[4], p1[4];
#pragma unroll
      for (int r = 0; r < 4; ++r) {
        p0[r] = __expf(sc0[r] - m_reg);
        p1[r] = __expf(sc1[r] - m_reg);
      }
      float ps = ((p0[0] + p0[1]) + (p0[2] + p0[3])) +
                 ((p1[0] + p1[1]) + (p1[2] + p1[3]));
      ps += __shfl_xor(ps, 16);
      ps += __shfl_xor(ps, 32);
      l_reg += ps;
      // P write: row=qrow, keys kh*32+lg*4+r (+16 for s1); swizzle (row&7)<<4
      char* pb = (char*)p_lds + row * 128;
      const int sw = (row & 7) << 4;
      const int off = kh * 64 + lg * 8;
      *(ushort4*)(pb + (off ^ sw))        = pack4(p0[0], p0[1], p0[2], p0[3]);
      *(ushort4*)(pb + ((off + 32) ^ sw)) = pack4(p1[0], p1[1], p1[2], p1[3]);
    }

    if (it + 1 < ITERS) {
      asm volatile("s_waitcnt vmcnt(8)" ::: "memory");  // V(t) landed (K(t+1)=8 out)
    } else {
      asm volatile("s_waitcnt vmcnt(0)" ::: "memory");  // drain V(t)
    }
    asm volatile("s_waitcnt lgkmcnt(0)" ::: "memory");  // p_lds/osc/flag visible
    __builtin_amdgcn_s_barrier();                       // bar-C

    // ---- PV (32x32x16): rows rg_pv*32.., cols cg*128.. ----
    {
      if (flag_st[rg_pv * 2] | flag_st[rg_pv * 2 + 1]) {
        float ov[16];
#pragma unroll
        for (int r = 0; r < 16; ++r)
          ov[r] = osc_st[rg_pv * 32 + (r & 3) + 8 * (r >> 2) + 4 * hi];
#pragma unroll
        for (int t = 0; t < 4; ++t)
#pragma unroll
          for (int r = 0; r < 16; ++r) oacc[t][r] *= ov[r];
      }
      const int arow = rg_pv * 32 + l31;
      const char* prow = (const char*)p_lds + arow * 128;
      const int psw = (arow & 7) << 4;
      __builtin_amdgcn_s_setprio(1);
#pragma unroll
      for (int c = 0; c < 4; ++c) {
        short8 pa = *(const short8*)(prow + ((c * 32 + hi * 16) ^ psw));
#pragma unroll
        for (int t = 0; t < 4; ++t) {
          int vrow = cg * 128 + t * 32 + l31;
          short8 vf = *(const short8*)((const char*)vtt + vrow * 128 +
                                       ((c * 32 + hi * 16) ^ ((vrow & 7) << 4)));
          oacc[t] = __builtin_amdgcn_mfma_f32_32x32x16_bf16(pa, vf, oacc[t], 0, 0, 0);
        }
      }
      __builtin_amdgcn_s_setprio(0);
    }
    asm volatile("s_waitcnt lgkmcnt(0)" ::: "memory");  // vtt/p reads done
    __builtin_amdgcn_s_barrier();                       // bar-D: vtt free
  }

  // ---- epilogue: merge l across kh, write opart + ml ----
  if (lane < 16) {
    l_st[kh][rg * 16 + lane] = l_reg;
    if (kh == 0) mx_st[0][rg * 16 + lane] = m_reg;
  }
  __syncthreads();
  {
    float* op = opart + ((size_t)sp * SEQ + qrow0 + rg_pv * 32) * DIM + cg * 128;
#pragma unroll
    for (int t = 0; t < 4; ++t)
#pragma unroll
      for (int r = 0; r < 16; ++r) {
        int crow = (r & 3) + 8 * (r >> 2) + 4 * hi;
        op[(size_t)crow * DIM + t * 32 + l31] = oacc[t][r];
      }
  }
  if (tid < BQ) {
    size_t base = ((size_t)sp * SEQ + qrow0 + tid) * 2;
    ml[base]     = mx_st[0][tid];
    ml[base + 1] = l_st[0][tid] + l_st[1][tid];
  }
}

// ---------- combine split partials ----------
__global__ void combine(const float* __restrict__ opart, const float* __restrict__ ml,
                        float* __restrict__ out) {
  int gid = blockIdx.x * 256 + threadIdx.x;
  int row = gid >> 7;
  int dv  = (gid & 127) * 4;
  float m[SPLITS], l[SPLITS], wgt[SPLITS];
  float M = -INFINITY;
#pragma unroll
  for (int i = 0; i < SPLITS; ++i) {
    m[i] = ml[((size_t)i * SEQ + row) * 2];
    l[i] = ml[((size_t)i * SEQ + row) * 2 + 1];
    M = fmaxf(M, m[i]);
  }
  float L = 0.f;
#pragma unroll
  for (int i = 0; i < SPLITS; ++i) { wgt[i] = __expf(m[i] - M); L += l[i] * wgt[i]; }
  float inv = 1.f / L;
  float4 acc = {0.f, 0.f, 0.f, 0.f};
#pragma unroll
  for (int i = 0; i < SPLITS; ++i) {
    float4 o = *(const float4*)(opart + ((size_t)i * SEQ + row) * DIM + dv);
    acc.x += o.x * wgt[i]; acc.y += o.y * wgt[i];
    acc.z += o.z * wgt[i]; acc.w += o.w * wgt[i];
  }
  acc.x *= inv; acc.y *= inv; acc.z *= inv; acc.w *= inv;
  *(float4*)(out + (size_t)row * DIM + dv) = acc;
}

// ---------- fallback if ws too small ----------
__global__ __launch_bounds__(512) void attn_fused_fb(
    const float* __restrict__ q, const float* __restrict__ k,
    const float* __restrict__ v, float* __restrict__ out) {
  __shared__ float s_lds[16][128];
  __shared__ __align__(16) unsigned short p_lds[16 * 128];
  __shared__ float m_st[16], l_st[16], osc_st[16];
  const int tid = threadIdx.x, lane = tid & 63, w = tid >> 6;
  const int lr = lane & 15, lg = lane >> 4, qb = blockIdx.x * 16;
  if (tid < 16) { m_st[tid] = -INFINITY; l_st[tid] = 0.f; }
  short8 qf[16];
  {
    const float* qp = q + (size_t)(qb + lr) * DIM + lg * 8;
#pragma unroll
    for (int c = 0; c < 16; ++c)
      qf[c] = pack8(*(const float4*)(qp + c * 32), *(const float4*)(qp + c * 32 + 4));
  }
  f32x4 oacc[4] = {};
  __syncthreads();
  for (int it = 0; it < SEQ / 128; ++it) {
    const int kb = it * 128;
    {
      const float* kp = k + (size_t)(kb + w * 16 + lr) * DIM + lg * 8;
      f32x4 sacc = {};
#pragma unroll
      for (int c = 0; c < 16; ++c) {
        short8 kf = pack8(*(const float4*)(kp + c * 32), *(const float4*)(kp + c * 32 + 4));
        sacc = __builtin_amdgcn_mfma_f32_16x16x32_bf16(qf[c], kf, sacc, 0, 0, 0);
      }
#pragma unroll
      for (int r = 0; r < 4; ++r) s_lds[lg * 4 + r][w * 16 + lr] = sacc[r] * SCALE;
    }
    __syncthreads();
    {
      const int srow = tid >> 5, sj = tid & 31;
      float4 sv = *(const float4*)&s_lds[srow][sj * 4];
      float tmax = fmaxf(fmaxf(sv.x, sv.y), fmaxf(sv.z, sv.w));
#pragma unroll
      for (int m = 16; m >= 1; m >>= 1) tmax = fmaxf(tmax, __shfl_xor(tmax, m));
      float mold = m_st[srow], mnew = fmaxf(mold, tmax);
      float p0 = __expf(sv.x - mnew), p1 = __expf(sv.y - mnew);
      float p2 = __expf(sv.z - mnew), p3 = __expf(sv.w - mnew);
      float psum = (p0 + p1) + (p2 + p3);
#pragma unroll
      for (int m = 16; m >= 1; m >>= 1) psum += __shfl_xor(psum, m);
      if (sj == 0) {
        float sc = __expf(mold - mnew);
        l_st[srow] = l_st[srow] * sc + psum; m_st[srow] = mnew; osc_st[srow] = sc;
      }
      ushort4 pb;
      pb.x = (unsigned short)f2bf(p0); pb.y = (unsigned short)f2bf(p1);
      pb.z = (unsigned short)f2bf(p2); pb.w = (unsigned short)f2bf(p3);
      int lin = srow * 256 + sj * 8;
      *(ushort4*)((char*)p_lds + (lin ^ ((srow & 7) << 4))) = pb;
    }
    __syncthreads();
    {
      float osc[4];
#pragma unroll
      for (int r = 0; r < 4; ++r) osc[r] = osc_st[lg * 4 + r];
#pragma unroll
      for (int ct = 0; ct < 4; ++ct)
#pragma unroll
        for (int r = 0; r < 4; ++r) oacc[ct][r] *= osc[r];
#pragma unroll
      for (int kc = 0; kc < 4; ++kc) {
        int lin = lr * 256 + (kc * 32 + 8 * lg) * 2;
        short8 pf = *(const short8*)((const char*)p_lds + (lin ^ ((lr & 7) << 4)));
        const float* vp0 = v + (size_t)(kb + kc * 32 + 8 * lg) * DIM + w * 64 + lr;
#pragma unroll
        for (int ct = 0; ct < 4; ++ct) {
          const float* vp = vp0 + ct * 16;
          short8 vf;
#pragma unroll
          for (int jj = 0; jj < 8; ++jj) vf[jj] = f2bf(vp[(size_t)jj * DIM]);
          oacc[ct] = __builtin_amdgcn_mfma_f32_16x16x32_bf16(pf, vf, oacc[ct], 0, 0, 0);
        }
      }
    }
    __syncthreads();
  }
  {
    float linv[4];
#pragma unroll
    for (int r = 0; r < 4; ++r) linv[r] = 1.f / l_st[lg * 4 + r];
#pragma unroll
    for (int ct = 0; ct < 4; ++ct)
#pragma unroll
      for (int r = 0; r < 4; ++r)
        out[(size_t)(qb + lg * 4 + r) * DIM + w * 64 + ct * 16 + lr] =
            oacc[ct][r] * linv[r];
  }
}

extern "C" void kernel_launch(void* const* d_in, const int* in_sizes, int n_in,
                              void* d_out, int out_size, void* d_ws, size_t ws_size,
                              hipStream_t stream) {
  (void)in_sizes; (void)n_in; (void)out_size;
  const float* q = (const float*)d_in[0];
  const float* k = (const float*)d_in[1];
  const float* v = (const float*)d_in[2];
  float* out = (float*)d_out;

  const size_t kbf_elems = (size_t)SEQ * DIM;
  const size_t vt_elems  = (size_t)DIM * SEQ;
  const size_t op_elems  = (size_t)SPLITS * SEQ * DIM;
  const size_t ml_elems  = (size_t)SPLITS * SEQ * 2;
  const size_t need = kbf_elems * 2 + vt_elems * 2 + op_elems * 4 + ml_elems * 4;

  if (ws_size >= need) {
    ushort* kbf  = (ushort*)d_ws;
    ushort* vtb  = kbf + kbf_elems;
    float* opart = (float*)(vtb + vt_elems);
    float* ml    = opart + op_elems;

    cvt_bf16<<<(SEQ * DIM / 8 + 255) / 256, 256, 0, stream>>>(k, kbf, SEQ * DIM / 8);
    transpose_bf16<<<(SEQ / 64) * (DIM / 64), 256, 0, stream>>>(v, vtb);
    attn_split<<<(SEQ / BQ) * SPLITS, 512, 0, stream>>>(q, kbf, vtb, opart, ml);
    combine<<<(SEQ * DIM / 4) / 256, 256, 0, stream>>>(opart, ml, out);
  } else {
    attn_fused_fb<<<SEQ / 16, 512, 0, stream>>>(q, k, v, out);
  }
}